// Round 11
// baseline (66.295 us; speedup 1.0000x reference)
//
#include <hip/hip_runtime.h>

#define DIMS 128
#define KTOP 16
#define SMAX 2048     // max MAXG supported by top-k kernel
#define SLICE 64      // candidates per score block
#define CK 64         // s_keyT row stride in dwords (unpadded; 2-way = free)
#define CQ 16         // s_qT row stride in dwords
#define QT 16         // queries per chunk
#define NTHR 128
#define QLMAX 2048    // max queries per partition supported in LDS

__device__ __forceinline__ unsigned long long packsim(float v, int g) {
    unsigned u = __float_as_uint(v);
    u = (u & 0x80000000u) ? ~u : (u | 0x80000000u);
    return ((unsigned long long)u << 32) | (unsigned)(0xFFFFFFFFu - (unsigned)g);
}

// ---- Kernel 1: self-bucketing register-tiled GEMM, 16q x 64c per block ----
__global__ __launch_bounds__(NTHR)
void score_kernel(const float* __restrict__ query,
                  const float* __restrict__ keys,
                  const int*   __restrict__ cached_groups,
                  const int*   __restrict__ hard_assign,
                  float* __restrict__ sims,
                  int B, int N, int MAXG, int nslice)
{
    __shared__ float s_keyT[DIMS * CK];   // 32 KB, [d][c]
    __shared__ float s_qT[DIMS * CQ];     //  8 KB, [d][q]
    __shared__ float s_inv[SLICE];
    __shared__ int   s_g[SLICE];
    __shared__ int   s_qb[QT];
    __shared__ int   s_ql[QLMAX];         //  8 KB
    __shared__ int   s_cnt;

    const int p = blockIdx.x / nslice;
    const int s = blockIdx.x % nslice;
    const int t = threadIdx.x;

    // ---- wave-0 ballot scan: build ascending query list for partition p ----
    if (t < 64) {
        int running = 0;
        for (int r0 = 0; r0 < B; r0 += 64) {
            const int b = r0 + t;
            const bool match = (b < B) && (hard_assign[b] == p);
            const unsigned long long mask = __ballot(match);
            if (match) {
                const int pre = __popcll(mask & ((1ull << t) - 1ull));
                if (running + pre < QLMAX) s_ql[running + pre] = b;
            }
            running += __popcll(mask);
        }
        if (t == 0) s_cnt = (running < QLMAX) ? running : QLMAX;
    }
    __syncthreads();
    const int cnt = s_cnt;
    if (cnt == 0) return;

    const int base = s * SLICE;
    const int* gp = cached_groups + (size_t)p * MAXG;

    // ---- stage keys: 2 threads per candidate row (64 dims each) ----
    {
        const int r    = t >> 1;          // candidate 0..63
        const int half = t & 1;           // dim half
        const int cand = (base + r < MAXG) ? gp[base + r] : -1;
        if (half == 0) s_g[r] = cand;
        const int sf = cand < 0 ? 0 : (cand > N - 1 ? N - 1 : cand);
        const float* kr = keys + (size_t)sf * DIMS + half * 64;
        float ks = 0.0f;
        #pragma unroll
        for (int h = 0; h < 2; ++h) {     // 2 batches of 8 b128 loads (deep MLP)
            float4 v[8];
            #pragma unroll
            for (int i = 0; i < 8; ++i)
                v[i] = *(const float4*)(kr + h * 32 + i * 4);
            #pragma unroll
            for (int i = 0; i < 8; ++i) {
                const int d = half * 64 + h * 32 + i * 4;
                ks += v[i].x * v[i].x + v[i].y * v[i].y
                    + v[i].z * v[i].z + v[i].w * v[i].w;
                s_keyT[(d + 0) * CK + r] = v[i].x;
                s_keyT[(d + 1) * CK + r] = v[i].y;
                s_keyT[(d + 2) * CK + r] = v[i].z;
                s_keyT[(d + 3) * CK + r] = v[i].w;
            }
        }
        ks += __shfl_xor(ks, 1, 64);      // pair-reduce the two halves
        if (half == 0) s_inv[r] = 1.0f / fmaxf(sqrtf(ks), 1e-12f);
    }

    const int q0 = (t >> 4) * 2;          // 0,2,..,14
    const int c0 = (t & 15) * 4;          // 0,4,..,60

    for (int qbase = 0; qbase < cnt; qbase += QT) {
        // ---- stage QT query rows transposed: thread (q=t&15, dblk=t>>4) ----
        {
            const int q    = t & 15;
            const int dblk = t >> 4;      // 0..7, 16 dims each
            const int ii = qbase + q;
            const int sq = s_ql[(ii < cnt) ? ii : (cnt - 1)];  // dup tail, masked
            if (dblk == 0) s_qb[q] = sq;
            const float* qr = query + (size_t)sq * DIMS + dblk * 16;
            #pragma unroll
            for (int i = 0; i < 4; ++i) {
                const float4 v = *(const float4*)(qr + i * 4);
                const int d = dblk * 16 + i * 4;
                s_qT[(d + 0) * CQ + q] = v.x;
                s_qT[(d + 1) * CQ + q] = v.y;
                s_qT[(d + 2) * CQ + q] = v.z;
                s_qT[(d + 3) * CQ + q] = v.w;
            }
        }
        __syncthreads();   // first iter: also covers key staging / ballot scan

        float acc[2][4];
        #pragma unroll
        for (int a = 0; a < 2; ++a)
            #pragma unroll
            for (int bb = 0; bb < 4; ++bb) acc[a][bb] = 0.0f;

        // A-read: b64 broadcast; B-read: b128 2-way (free)
        #pragma unroll 8
        for (int k = 0; k < DIMS; ++k) {
            const float2 aq = *(const float2*)&s_qT[k * CQ + q0];
            const float4 bk = *(const float4*)&s_keyT[k * CK + c0];
            acc[0][0] += aq.x * bk.x; acc[0][1] += aq.x * bk.y;
            acc[0][2] += aq.x * bk.z; acc[0][3] += aq.x * bk.w;
            acc[1][0] += aq.y * bk.x; acc[1][1] += aq.y * bk.y;
            acc[1][2] += aq.y * bk.z; acc[1][3] += aq.y * bk.w;
        }

        // ---- epilogue: scale by key inv-norm, mask invalid, coalesced f4 ----
        const float4 inv = *(const float4*)&s_inv[c0];
        const int4   gv  = *(const int4*)&s_g[c0];
        #pragma unroll
        for (int qi = 0; qi < 2; ++qi) {
            const int ii = qbase + q0 + qi;
            if (ii < cnt) {
                const int b = s_qb[q0 + qi];
                float4 o;
                o.x = (gv.x >= 0) ? acc[qi][0] * inv.x : -1.0e9f;
                o.y = (gv.y >= 0) ? acc[qi][1] * inv.y : -1.0e9f;
                o.z = (gv.z >= 0) ? acc[qi][2] * inv.z : -1.0e9f;
                o.w = (gv.w >= 0) ? acc[qi][3] * inv.w : -1.0e9f;
                float* dst = sims + (size_t)b * MAXG + base + c0;
                if (base + c0 + 3 < MAXG) {
                    *(float4*)dst = o;
                } else {
                    if (base + c0 + 0 < MAXG) dst[0] = o.x;
                    if (base + c0 + 1 < MAXG) dst[1] = o.y;
                    if (base + c0 + 2 < MAXG) dst[2] = o.z;
                }
            }
        }

        if (qbase + QT < cnt) __syncthreads();   // protect s_qT rewrite
    }
}

// ---------------- Kernel 2: top-16 per query + output gather ----------------
#define CASW(x,y) { if ((x) < (y)) { const unsigned long long _t = (x); (x) = (y); (y) = _t; } }

__global__ __launch_bounds__(256)
void topk_gather_kernel(const float* __restrict__ keys,
                        const float* __restrict__ vals,
                        const float* __restrict__ labels,
                        const int*   __restrict__ hard_assign,
                        const int*   __restrict__ cached_groups,
                        const int*   __restrict__ group_sizes,
                        const float* __restrict__ sims,
                        float* __restrict__ out,
                        int B, int MAXG)
{
    const int b = blockIdx.x, t = threadIdx.x;
    const int lane = t & 63, w = t >> 6;
    const int sub = t & 15, cg = t >> 4;

    __shared__ unsigned long long s_merge[64];
    __shared__ int s_wing[KTOP];

    const int p = hard_assign[b];
    const int grpsz = group_sizes[p];
    const bool normal = (grpsz >= KTOP);
    const int* gptr = cached_groups + (size_t)p * MAXG;
    const float* simrow = sims + (size_t)b * MAXG;

    // phase A: per-wave top-16 of 512, sorted-heads (keys globally unique)
    unsigned long long k0, k1, k2, k3, k4, k5, k6, k7;
    {
        #define LDK(j) ({ const int g = w * (SMAX / 4) + (j) * 64 + lane;          \
                          const float v = (g < MAXG) ? simrow[g] : -3.0e38f;       \
                          packsim(v, g); })
        k0 = LDK(0); k1 = LDK(1); k2 = LDK(2); k3 = LDK(3);
        k4 = LDK(4); k5 = LDK(5); k6 = LDK(6); k7 = LDK(7);
        #undef LDK
    }
    // Batcher odd-even mergesort, 19 comparators, descending
    CASW(k0,k1) CASW(k2,k3) CASW(k4,k5) CASW(k6,k7)
    CASW(k0,k2) CASW(k1,k3) CASW(k4,k6) CASW(k5,k7)
    CASW(k1,k2) CASW(k5,k6)
    CASW(k0,k4) CASW(k1,k5) CASW(k2,k6) CASW(k3,k7)
    CASW(k2,k4) CASW(k3,k5)
    CASW(k1,k2) CASW(k3,k4) CASW(k5,k6)

    #pragma unroll 1
    for (int r = 0; r < KTOP; ++r) {
        unsigned long long wm = k0;
        #pragma unroll
        for (int off = 1; off < 64; off <<= 1) {
            const unsigned long long o = __shfl_xor(wm, off, 64);
            wm = (o > wm) ? o : wm;
        }
        if (lane == 0) s_merge[w * KTOP + r] = wm;
        if (k0 == wm) {                  // unique keys -> exactly one winner
            k0 = k1; k1 = k2; k2 = k3; k3 = k4;
            k4 = k5; k5 = k6; k6 = k7; k7 = 0ull;
        }
    }
    __syncthreads();

    // phase B: wave 0 merges 64 survivors -> global top-16 in order
    if (w == 0) {
        unsigned long long u = s_merge[lane];
        #pragma unroll 1
        for (int r = 0; r < KTOP; ++r) {
            unsigned long long m = u;
            #pragma unroll
            for (int off = 1; off < 64; off <<= 1) {
                const unsigned long long o = __shfl_xor(m, off, 64);
                m = (o > m) ? o : m;
            }
            if (lane == 0)
                s_wing[r] = (int)(0xFFFFFFFFu - (unsigned)(m & 0xFFFFFFFFull));
            if (u == m) u = 0ull;
        }
    }
    __syncthreads();

    // outputs: group cg handles winner #cg
    const int g    = s_wing[cg];
    const int cand = gptr[g];
    const int idx  = cand < 0 ? 0 : cand;

    const size_t BK = (size_t)B * KTOP;
    float* out_nk = out;
    float* out_nv = out + BK * DIMS;
    float* out_nl = out + 2 * BK * DIMS;
    float* out_id = out_nl + BK;

    const size_t od = ((size_t)b * KTOP + cg) * DIMS + sub * 8;
    if (normal) {
        const float* kr = keys + (size_t)idx * DIMS + sub * 8;
        const float* vr = vals + (size_t)idx * DIMS + sub * 8;
        *(float4*)(out_nk + od)     = *(const float4*)(kr);
        *(float4*)(out_nk + od + 4) = *(const float4*)(kr + 4);
        *(float4*)(out_nv + od)     = *(const float4*)(vr);
        *(float4*)(out_nv + od + 4) = *(const float4*)(vr + 4);
        if (sub == 0) {
            out_nl[(size_t)b * KTOP + cg] = labels[idx];
            out_id[(size_t)b * KTOP + cg] = (float)idx;
        }
    } else {
        const float4 z = make_float4(0.f, 0.f, 0.f, 0.f);
        *(float4*)(out_nk + od)     = z;
        *(float4*)(out_nk + od + 4) = z;
        *(float4*)(out_nv + od)     = z;
        *(float4*)(out_nv + od + 4) = z;
        if (sub == 0) {
            out_nl[(size_t)b * KTOP + cg] = 0.0f;
            out_id[(size_t)b * KTOP + cg] = 0.0f;
        }
    }
}

extern "C" void kernel_launch(void* const* d_in, const int* in_sizes, int n_in,
                              void* d_out, int out_size, void* d_ws, size_t ws_size,
                              hipStream_t stream) {
    const float* query  = (const float*)d_in[0];
    const float* keys   = (const float*)d_in[1];
    const float* vals   = (const float*)d_in[2];
    const float* labels = (const float*)d_in[3];
    const int* hard_assign   = (const int*)d_in[4];
    const int* cached_groups = (const int*)d_in[5];
    const int* group_sizes   = (const int*)d_in[6];

    const int B = in_sizes[0] / DIMS;
    const int N = in_sizes[1] / DIMS;
    const int P = in_sizes[6];
    const int MAXG = in_sizes[5] / P;
    const int nslice = (MAXG + SLICE - 1) / SLICE;

    float* sims = (float*)d_ws;   // B*MAXG floats

    score_kernel<<<P * nslice, NTHR, 0, stream>>>(
        query, keys, cached_groups, hard_assign, sims, B, N, MAXG, nslice);

    topk_gather_kernel<<<B, 256, 0, stream>>>(
        keys, vals, labels, hard_assign, cached_groups, group_sizes, sims,
        (float*)d_out, B, MAXG);
}

// Round 12
// 64.414 us; speedup vs baseline: 1.0292x; 1.0292x over previous
//
#include <hip/hip_runtime.h>

#define DIMS 128
#define KTOP 16
#define SMAX 2048     // max MAXG supported by top-k kernel
#define SLICE 128     // candidates per score block
#define CKS 128       // s_keyT row stride in dwords (unpadded)
#define CQS 16        // s_qT row stride in dwords (unpadded)
#define QT 16         // queries per chunk
#define NTHR 128

__device__ __forceinline__ unsigned long long packsim(float v, int g) {
    unsigned u = __float_as_uint(v);
    u = (u & 0x80000000u) ? ~u : (u | 0x80000000u);
    return ((unsigned long long)u << 32) | (unsigned)(0xFFFFFFFFu - (unsigned)g);
}

// ---------------- Kernel 0: zero + bucket queries, single block ----------------
__global__ __launch_bounds__(1024)
void bucket_kernel(const int* __restrict__ hard_assign,
                   int* __restrict__ qcount, int* __restrict__ qlist, int B, int P)
{
    const int t = threadIdx.x;
    for (int i = t; i < P; i += 1024) qcount[i] = 0;
    __syncthreads();
    for (int b = t; b < B; b += 1024) {
        const int p = hard_assign[b];
        const int slot = atomicAdd(&qcount[p], 1);
        qlist[(size_t)p * B + slot] = b;
    }
}

// ---- Kernel 1: register-tiled GEMM, 16q x 128c per block, 4q x 4c per thread ----
// Static LDS 74.8 KB -> 2 blocks/CU (4 waves, all SIMDs fed). Conflict-free reads.
__global__ __launch_bounds__(NTHR)
void score_kernel(const float* __restrict__ query,
                  const float* __restrict__ keys,
                  const int*   __restrict__ cached_groups,
                  const int*   __restrict__ qcount,
                  const int*   __restrict__ qlist,
                  float* __restrict__ sims,
                  int B, int N, int MAXG, int nslice)
{
    __shared__ float s_keyT[DIMS * CKS];  // 64 KB, [d][c]
    __shared__ float s_qT[DIMS * CQS];    //  8 KB, [d][q]
    __shared__ float s_inv[SLICE];
    __shared__ int   s_g[SLICE];
    __shared__ int   s_qb[QT];

    const int p = blockIdx.x / nslice;
    const int s = blockIdx.x % nslice;
    const int cnt = qcount[p];
    if (cnt == 0) return;

    const int t = threadIdx.x;
    const int base = s * SLICE;
    const int* gp = cached_groups + (size_t)p * MAXG;
    const int* ql = qlist + (size_t)p * B;

    // ---- stage keys: one candidate row per thread; per-thread norm (no shuffles).
    // LDS writes: 64 lanes write consecutive c at fixed d -> 2/bank = free.
    {
        const int cand = (base + t < MAXG) ? gp[base + t] : -1;
        s_g[t] = cand;
        const int sf = cand < 0 ? 0 : (cand > N - 1 ? N - 1 : cand);
        const float* kr = keys + (size_t)sf * DIMS;
        float ks = 0.0f;
        #pragma unroll
        for (int h = 0; h < 4; ++h) {       // 4 batches of 8 b128 loads (deep MLP)
            float4 v[8];
            #pragma unroll
            for (int i = 0; i < 8; ++i)
                v[i] = *(const float4*)(kr + h * 32 + i * 4);
            #pragma unroll
            for (int i = 0; i < 8; ++i) {
                const int d = h * 32 + i * 4;
                ks += v[i].x * v[i].x + v[i].y * v[i].y
                    + v[i].z * v[i].z + v[i].w * v[i].w;
                s_keyT[(d + 0) * CKS + t] = v[i].x;
                s_keyT[(d + 1) * CKS + t] = v[i].y;
                s_keyT[(d + 2) * CKS + t] = v[i].z;
                s_keyT[(d + 3) * CKS + t] = v[i].w;
            }
        }
        s_inv[t] = 1.0f / fmaxf(sqrtf(ks), 1e-12f);
    }

    // thread tile: 4 queries x 4 candidates.
    // q-tile: (t>>4)&3 -> aq is a 16-lane broadcast of 4 distinct b128 addrs.
    // c-tile: (t&15) | ((t>>6)<<4) -> per wave, bk spans 64 consecutive dwords
    //         read by 4-lane broadcast groups: 2/bank = free.
    const int q0 = ((t >> 4) & 3) * 4;
    const int c0 = ((t & 15) | ((t >> 6) << 4)) * 4;

    for (int qbase = 0; qbase < cnt; qbase += QT) {
        // ---- stage QT query rows transposed: thread (q=t&15, dblk=t>>4) ----
        {
            const int q    = t & 15;
            const int dblk = t >> 4;        // 0..7, 16 dims each
            const int ii = qbase + q;
            const int sq = ql[(ii < cnt) ? ii : (cnt - 1)];   // dup tail, masked
            if (dblk == 0) s_qb[q] = sq;
            const float* qr = query + (size_t)sq * DIMS + dblk * 16;
            #pragma unroll
            for (int i = 0; i < 4; ++i) {
                const float4 v = *(const float4*)(qr + i * 4);
                const int d = dblk * 16 + i * 4;
                s_qT[(d + 0) * CQS + q] = v.x;
                s_qT[(d + 1) * CQS + q] = v.y;
                s_qT[(d + 2) * CQS + q] = v.z;
                s_qT[(d + 3) * CQS + q] = v.w;
            }
        }
        __syncthreads();   // first iter: also covers key staging

        float acc[4][4];
        #pragma unroll
        for (int a = 0; a < 4; ++a)
            #pragma unroll
            for (int bb = 0; bb < 4; ++bb) acc[a][bb] = 0.0f;

        #pragma unroll 4
        for (int k = 0; k < DIMS; ++k) {
            const float4 aq = *(const float4*)&s_qT[k * CQS + q0];
            const float4 bk = *(const float4*)&s_keyT[k * CKS + c0];
            acc[0][0] += aq.x * bk.x; acc[0][1] += aq.x * bk.y;
            acc[0][2] += aq.x * bk.z; acc[0][3] += aq.x * bk.w;
            acc[1][0] += aq.y * bk.x; acc[1][1] += aq.y * bk.y;
            acc[1][2] += aq.y * bk.z; acc[1][3] += aq.y * bk.w;
            acc[2][0] += aq.z * bk.x; acc[2][1] += aq.z * bk.y;
            acc[2][2] += aq.z * bk.z; acc[2][3] += aq.z * bk.w;
            acc[3][0] += aq.w * bk.x; acc[3][1] += aq.w * bk.y;
            acc[3][2] += aq.w * bk.z; acc[3][3] += aq.w * bk.w;
        }

        // ---- epilogue: scale by key inv-norm, mask invalid, coalesced f4 ----
        const float4 inv = *(const float4*)&s_inv[c0];
        const int4   gv  = *(const int4*)&s_g[c0];
        #pragma unroll
        for (int qi = 0; qi < 4; ++qi) {
            const int ii = qbase + q0 + qi;
            if (ii < cnt) {
                const int b = s_qb[q0 + qi];
                float4 o;
                o.x = (gv.x >= 0) ? acc[qi][0] * inv.x : -1.0e9f;
                o.y = (gv.y >= 0) ? acc[qi][1] * inv.y : -1.0e9f;
                o.z = (gv.z >= 0) ? acc[qi][2] * inv.z : -1.0e9f;
                o.w = (gv.w >= 0) ? acc[qi][3] * inv.w : -1.0e9f;
                float* dst = sims + (size_t)b * MAXG + base + c0;
                if (base + c0 + 3 < MAXG) {
                    *(float4*)dst = o;
                } else {
                    if (base + c0 + 0 < MAXG) dst[0] = o.x;
                    if (base + c0 + 1 < MAXG) dst[1] = o.y;
                    if (base + c0 + 2 < MAXG) dst[2] = o.z;
                }
            }
        }

        if (qbase + QT < cnt) __syncthreads();   // protect s_qT rewrite
    }
}

// ---------------- Kernel 2: top-16 per query + output gather ----------------
#define CASW(x,y) { if ((x) < (y)) { const unsigned long long _t = (x); (x) = (y); (y) = _t; } }

__global__ __launch_bounds__(256)
void topk_gather_kernel(const float* __restrict__ keys,
                        const float* __restrict__ vals,
                        const float* __restrict__ labels,
                        const int*   __restrict__ hard_assign,
                        const int*   __restrict__ cached_groups,
                        const int*   __restrict__ group_sizes,
                        const float* __restrict__ sims,
                        float* __restrict__ out,
                        int B, int MAXG)
{
    const int b = blockIdx.x, t = threadIdx.x;
    const int lane = t & 63, w = t >> 6;
    const int sub = t & 15, cg = t >> 4;

    __shared__ unsigned long long s_merge[64];
    __shared__ int s_wing[KTOP];

    const int p = hard_assign[b];
    const int grpsz = group_sizes[p];
    const bool normal = (grpsz >= KTOP);
    const int* gptr = cached_groups + (size_t)p * MAXG;
    const float* simrow = sims + (size_t)b * MAXG;

    // phase A: per-wave top-16 of 512, sorted-heads (keys globally unique)
    unsigned long long k0, k1, k2, k3, k4, k5, k6, k7;
    {
        #define LDK(j) ({ const int g = w * (SMAX / 4) + (j) * 64 + lane;          \
                          const float v = (g < MAXG) ? simrow[g] : -3.0e38f;       \
                          packsim(v, g); })
        k0 = LDK(0); k1 = LDK(1); k2 = LDK(2); k3 = LDK(3);
        k4 = LDK(4); k5 = LDK(5); k6 = LDK(6); k7 = LDK(7);
        #undef LDK
    }
    // Batcher odd-even mergesort, 19 comparators, descending
    CASW(k0,k1) CASW(k2,k3) CASW(k4,k5) CASW(k6,k7)
    CASW(k0,k2) CASW(k1,k3) CASW(k4,k6) CASW(k5,k7)
    CASW(k1,k2) CASW(k5,k6)
    CASW(k0,k4) CASW(k1,k5) CASW(k2,k6) CASW(k3,k7)
    CASW(k2,k4) CASW(k3,k5)
    CASW(k1,k2) CASW(k3,k4) CASW(k5,k6)

    #pragma unroll 1
    for (int r = 0; r < KTOP; ++r) {
        unsigned long long wm = k0;
        #pragma unroll
        for (int off = 1; off < 64; off <<= 1) {
            const unsigned long long o = __shfl_xor(wm, off, 64);
            wm = (o > wm) ? o : wm;
        }
        if (lane == 0) s_merge[w * KTOP + r] = wm;
        if (k0 == wm) {                  // unique keys -> exactly one winner
            k0 = k1; k1 = k2; k2 = k3; k3 = k4;
            k4 = k5; k5 = k6; k6 = k7; k7 = 0ull;
        }
    }
    __syncthreads();

    // phase B: wave 0 merges 64 survivors -> global top-16 in order
    if (w == 0) {
        unsigned long long u = s_merge[lane];
        #pragma unroll 1
        for (int r = 0; r < KTOP; ++r) {
            unsigned long long m = u;
            #pragma unroll
            for (int off = 1; off < 64; off <<= 1) {
                const unsigned long long o = __shfl_xor(m, off, 64);
                m = (o > m) ? o : m;
            }
            if (lane == 0)
                s_wing[r] = (int)(0xFFFFFFFFu - (unsigned)(m & 0xFFFFFFFFull));
            if (u == m) u = 0ull;
        }
    }
    __syncthreads();

    // outputs: group cg handles winner #cg
    const int g    = s_wing[cg];
    const int cand = gptr[g];
    const int idx  = cand < 0 ? 0 : cand;

    const size_t BK = (size_t)B * KTOP;
    float* out_nk = out;
    float* out_nv = out + BK * DIMS;
    float* out_nl = out + 2 * BK * DIMS;
    float* out_id = out_nl + BK;

    const size_t od = ((size_t)b * KTOP + cg) * DIMS + sub * 8;
    if (normal) {
        const float* kr = keys + (size_t)idx * DIMS + sub * 8;
        const float* vr = vals + (size_t)idx * DIMS + sub * 8;
        *(float4*)(out_nk + od)     = *(const float4*)(kr);
        *(float4*)(out_nk + od + 4) = *(const float4*)(kr + 4);
        *(float4*)(out_nv + od)     = *(const float4*)(vr);
        *(float4*)(out_nv + od + 4) = *(const float4*)(vr + 4);
        if (sub == 0) {
            out_nl[(size_t)b * KTOP + cg] = labels[idx];
            out_id[(size_t)b * KTOP + cg] = (float)idx;
        }
    } else {
        const float4 z = make_float4(0.f, 0.f, 0.f, 0.f);
        *(float4*)(out_nk + od)     = z;
        *(float4*)(out_nk + od + 4) = z;
        *(float4*)(out_nv + od)     = z;
        *(float4*)(out_nv + od + 4) = z;
        if (sub == 0) {
            out_nl[(size_t)b * KTOP + cg] = 0.0f;
            out_id[(size_t)b * KTOP + cg] = 0.0f;
        }
    }
}

extern "C" void kernel_launch(void* const* d_in, const int* in_sizes, int n_in,
                              void* d_out, int out_size, void* d_ws, size_t ws_size,
                              hipStream_t stream) {
    const float* query  = (const float*)d_in[0];
    const float* keys   = (const float*)d_in[1];
    const float* vals   = (const float*)d_in[2];
    const float* labels = (const float*)d_in[3];
    const int* hard_assign   = (const int*)d_in[4];
    const int* cached_groups = (const int*)d_in[5];
    const int* group_sizes   = (const int*)d_in[6];

    const int B = in_sizes[0] / DIMS;
    const int N = in_sizes[1] / DIMS;
    const int P = in_sizes[6];
    const int MAXG = in_sizes[5] / P;
    const int nslice = (MAXG + SLICE - 1) / SLICE;

    float* sims  = (float*)d_ws;                                // B*MAXG floats
    int* qcount  = (int*)((char*)d_ws + (size_t)B * MAXG * 4);  // P ints
    int* qlist   = qcount + P;                                  // P*B ints

    bucket_kernel<<<1, 1024, 0, stream>>>(hard_assign, qcount, qlist, B, P);

    score_kernel<<<P * nslice, NTHR, 0, stream>>>(
        query, keys, cached_groups, qcount, qlist, sims, B, N, MAXG, nslice);

    topk_gather_kernel<<<B, 256, 0, stream>>>(
        keys, vals, labels, hard_assign, cached_groups, group_sizes, sims,
        (float*)d_out, B, MAXG);
}